// Round 5
// baseline (766.671 us; speedup 1.0000x reference)
//
#include <hip/hip_runtime.h>

#define IMG_H 512
#define IMG_W 512
#define BATCH 32
#define TW 256            // columns per block (1 col/thread)
#define TH 32             // output rows per block
#define PITCHF 264        // floats per LDS row (262 used, pad to 264)
#define NBLK (2 * 16 * 32)

// Async global->LDS (4 B/lane). HW semantics: dest = readfirstlane(lds ptr)
// + lane*4. Only use with (a) all lanes active and slot linear in t, or
// (b) an active-lane PREFIX starting at lane 0.
__device__ __forceinline__ void gload_lds(const float* g, float* l) {
  __builtin_amdgcn_global_load_lds(
      (const __attribute__((address_space(1))) void*)g,
      (__attribute__((address_space(3))) void*)l, 4, 0, 0);
}

// One input row: horizontal 7-tap from LDS, vertical scatter into the mod-7
// register ring, emit completed output row. RR (and thus every acc index) is
// compile-time at each expansion. LO = lower-boundary chunk (r==RR==abs row).
#define ROW_BODY(RR, BUF, LO)                                                 \
  {                                                                           \
    float hx = 0.f, hy = 0.f, hxx = 0.f, hyy = 0.f, hxy = 0.f;                \
    _Pragma("unroll") for (int k = 0; k < 7; ++k) {                           \
      const float xv = xs[BUF][(RR)*PITCHF + t + k];                          \
      const float yv = ys[BUF][(RR)*PITCHF + t + k];                          \
      const float wx = w[k] * xv;                                             \
      const float wy = w[k] * yv;                                             \
      hx = fmaf(w[k], xv, hx);                                                \
      hy = fmaf(w[k], yv, hy);                                                \
      hxx = fmaf(wx, xv, hxx);                                                \
      hyy = fmaf(wy, yv, hyy);                                                \
      hxy = fmaf(wx, yv, hxy);                                                \
    }                                                                         \
    _Pragma("unroll") for (int tt = 0; tt < 7; ++tt) {                        \
      if (!(LO) || (RR) >= tt) {                                              \
        const int slot = (((RR)-tt) % 7 + 7) % 7;                             \
        const float wt = w[tt];                                               \
        acc[slot][0] = fmaf(wt, hx, acc[slot][0]);                            \
        acc[slot][1] = fmaf(wt, hy, acc[slot][1]);                            \
        acc[slot][2] = fmaf(wt, hxx, acc[slot][2]);                           \
        acc[slot][3] = fmaf(wt, hyy, acc[slot][3]);                           \
        acc[slot][4] = fmaf(wt, hxy, acc[slot][4]);                           \
      }                                                                       \
    }                                                                         \
    if (!(LO) || (RR) >= 6) {                                                 \
      const int slot = ((RR) + 1) % 7;                                        \
      const float mu_x = acc[slot][0];                                        \
      const float mu_y = acc[slot][1];                                        \
      const float mx2 = mu_x * mu_x;                                          \
      const float my2 = mu_y * mu_y;                                          \
      const float mxy = mu_x * mu_y;                                          \
      const float sxx = acc[slot][2] - mx2;                                   \
      const float syy = acc[slot][3] - my2;                                   \
      const float sxy = acc[slot][4] - mxy;                                   \
      const float num = (2.f * mxy + 1e-4f) * (2.f * sxy + 9e-4f);            \
      const float den = (mx2 + my2 + 1e-4f) * (sxx + syy + 9e-4f);            \
      tsum += num * __builtin_amdgcn_rcpf(den);                               \
      acc[slot][0] = acc[slot][1] = acc[slot][2] = acc[slot][3] =             \
          acc[slot][4] = 0.f;                                                 \
    }                                                                         \
  }

__global__ __launch_bounds__(256, 4) void ssim_main(
    const float* __restrict__ X, const float* __restrict__ Y,
    const float* __restrict__ K, float* __restrict__ partials) {
  __shared__ float xs[2][7 * PITCHF];   // 14784 B
  __shared__ float ys[2][7 * PITCHF];   // 14784 B
  __shared__ float wsum[4];

  const int t = threadIdx.x;
  const int x0 = blockIdx.x * TW;       // 0 or 256 (wave-uniform)
  const int y0 = blockIdx.y * TH;
  const size_t img = (size_t)IMG_H * IMG_W;
  const float* Xb = X + blockIdx.z * img;
  const float* Yb = Y + blockIdx.z * img;

  // Exact separable 1D weights from center row of the provided 7x7 kernel:
  // k[3][j] = w3*w_j, sum_j w_j = 1  =>  w_j = k[3][j] / sum_j k[3][j].
  float w[7];
  {
    float rs = 0.f;
#pragma unroll
    for (int j = 0; j < 7; ++j) { w[j] = K[3 * 7 + j]; rs += w[j]; }
    const float inv = 1.f / rs;
#pragma unroll
    for (int j = 0; j < 7; ++j) w[j] *= inv;
  }

  // LDS slot s of a row holds image column x0-3+s (s = 0..261).
  //  x0==0  : main (all lanes): gx[t]      -> slot 3+t   (cols 0..255)
  //           halo (t<3)      : gx[256+t]  -> slot 259+t (cols 256..258)
  //           zero slots 0..2 (cols -3..-1)
  //  x0==256: main (all lanes): gx[253+t]  -> slot t     (cols 253..508)
  //           halo (t<3)      : gx[509+t]  -> slot 256+t (cols 509..511)
  //           zero slots 259..261 (cols 512..514)
  // Main loads are fully active; halo loads have an active prefix {0,1,2} of
  // wave 0 -> readfirstlane base is lane 0's pointer. No shifted-base hazard.
  const bool left = (x0 == 0);
  const int cmain = left ? t : (x0 - 3 + t);
  const int smain = left ? (3 + t) : t;
  const int chalo = left ? (256 + t) : (509 + t);  // valid for t<3
  const int shalo = left ? (259 + t) : (256 + t);
  const int zslot = left ? t : (259 + t);          // t<3

  // Stage rows [y0-3+c0 .. +n-1] of both images into buffer `buf`, async.
  auto stage_chunk = [&](int c0, int buf, int n) {
#pragma unroll
    for (int i = 0; i < 7; ++i) {
      if (i < n) {
        const int gy = y0 - 3 + c0 + i;
        float* xrow = &xs[buf][i * PITCHF];
        float* yrow = &ys[buf][i * PITCHF];
        if (t < 3) { xrow[zslot] = 0.f; yrow[zslot] = 0.f; }
        if ((unsigned)gy < (unsigned)IMG_H) {   // wave-uniform
          const float* gx = Xb + (size_t)gy * IMG_W;
          const float* gv = Yb + (size_t)gy * IMG_W;
          gload_lds(gx + cmain, xrow + smain);
          gload_lds(gv + cmain, yrow + smain);
          if (t < 3) {
            gload_lds(gx + chalo, xrow + shalo);
            gload_lds(gv + chalo, yrow + shalo);
          }
        } else {  // OOB row -> zeros (SAME padding)
          xrow[t] = 0.f;
          yrow[t] = 0.f;
          if (t < 6) { xrow[256 + t] = 0.f; yrow[256 + t] = 0.f; }
        }
      }
    }
  };

  float acc[7][5];
#pragma unroll
  for (int s = 0; s < 7; ++s)
#pragma unroll
    for (int c = 0; c < 5; ++c) acc[s][c] = 0.f;
  float tsum = 0.f;

  // Pipeline: stage k+1 async, compute k; the compiler's vmcnt(0) drain at
  // each __syncthreads is the completion wait. One barrier per 7 rows.
  stage_chunk(0, 0, 7);
  __syncthreads();                       // chunk0 landed
  stage_chunk(7, 1, 7);
#pragma unroll
  for (int rr = 0; rr < 7; ++rr) ROW_BODY(rr, 0, true);   // rows 0..6
  __syncthreads();                       // chunk1 landed; buf0 free
  stage_chunk(14, 0, 7);
#pragma unroll
  for (int rr = 0; rr < 7; ++rr) ROW_BODY(rr, 1, false);  // rows 7..13
  __syncthreads();
  stage_chunk(21, 1, 7);
#pragma unroll
  for (int rr = 0; rr < 7; ++rr) ROW_BODY(rr, 0, false);  // rows 14..20
  __syncthreads();
  stage_chunk(28, 0, 7);
#pragma unroll
  for (int rr = 0; rr < 7; ++rr) ROW_BODY(rr, 1, false);  // rows 21..27
  __syncthreads();
  stage_chunk(35, 1, 3);                 // only rows 35..37 exist
#pragma unroll
  for (int rr = 0; rr < 7; ++rr) ROW_BODY(rr, 0, false);  // rows 28..34
  __syncthreads();
#pragma unroll
  for (int rr = 0; rr < 3; ++rr) ROW_BODY(rr, 1, false);  // rows 35..37

  // Block reduction -> one plain store per block (no atomics, no fences).
#pragma unroll
  for (int off = 32; off > 0; off >>= 1) tsum += __shfl_down(tsum, off);
  if ((t & 63) == 0) wsum[t >> 6] = tsum;
  __syncthreads();
  if (t == 0) {
    const int bid = blockIdx.x + 2 * (blockIdx.y + 16 * blockIdx.z);
    partials[bid] = wsum[0] + wsum[1] + wsum[2] + wsum[3];
  }
}

__global__ __launch_bounds__(256) void ssim_reduce(
    const float* __restrict__ partials, float* __restrict__ out) {
  __shared__ double wsum[4];
  const int t = threadIdx.x;
  double s = 0.0;
#pragma unroll
  for (int i = 0; i < NBLK / 256; ++i) s += (double)partials[t + 256 * i];
#pragma unroll
  for (int off = 32; off > 0; off >>= 1) s += __shfl_down(s, off);
  if ((t & 63) == 0) wsum[t >> 6] = s;
  __syncthreads();
  if (t == 0)
    out[0] = (float)((wsum[0] + wsum[1] + wsum[2] + wsum[3]) *
                     (1.0 / (double)((size_t)BATCH * IMG_H * IMG_W)));
}

extern "C" void kernel_launch(void* const* d_in, const int* in_sizes, int n_in,
                              void* d_out, int out_size, void* d_ws, size_t ws_size,
                              hipStream_t stream) {
  const float* X = (const float*)d_in[0];
  const float* Y = (const float*)d_in[1];
  const float* K = (const float*)d_in[2];
  float* out = (float*)d_out;
  float* partials = (float*)d_ws;   // NBLK floats, all rewritten every launch

  dim3 grid(IMG_W / TW, IMG_H / TH, BATCH);  // (2, 16, 32) = 1024 blocks
  hipLaunchKernelGGL(ssim_main, grid, dim3(256), 0, stream, X, Y, K, partials);
  hipLaunchKernelGGL(ssim_reduce, dim3(1), dim3(256), 0, stream, partials, out);
}

// Round 6
// 114.351 us; speedup vs baseline: 6.7045x; 6.7045x over previous
//
#include <hip/hip_runtime.h>

#define IMG_H 512
#define IMG_W 512
#define BATCH 32
#define TW 256            // columns per block (1 col/thread)
#define TH 16             // output rows per block
#define NROWS (TH + 6)    // 22 input rows streamed per tile
#define NBLK (2 * 32 * 32)  // 2048 blocks

__global__ __launch_bounds__(256) void ssim_main(
    const float* __restrict__ X, const float* __restrict__ Y,
    const float* __restrict__ K, float* __restrict__ partials) {
  __shared__ float2 sbuf[2][264];   // x,y interleaved; 262 used
  __shared__ float wsum[4];

  const int t = threadIdx.x;
  const int x0 = blockIdx.x * TW;
  const int y0 = blockIdx.y * TH;
  const size_t img = (size_t)IMG_H * IMG_W;
  const float* Xb = X + blockIdx.z * img;
  const float* Yb = Y + blockIdx.z * img;

  // Exact separable 1D weights from center row of the provided 7x7 kernel:
  // k[3][j] = w3*w_j, sum_j w_j = 1  =>  w_j = k[3][j] / sum_j k[3][j].
  float w[7];
  {
    float rs = 0.f;
#pragma unroll
    for (int j = 0; j < 7; ++j) { w[j] = K[3 * 7 + j]; rs += w[j]; }
    const float inv = 1.f / rs;
#pragma unroll
    for (int j = 0; j < 7; ++j) w[j] *= inv;
  }

  // Loop-invariant horizontal addressing (slot s = image col x0-3+s).
  const int g1 = x0 - 3 + t;
  const bool ok1 = (unsigned)g1 < (unsigned)IMG_W;
  const int g2 = g1 + TW;
  const bool ok2 = (t < 6) && ((unsigned)g2 < (unsigned)IMG_W);

  // mod-7 ring of 5-channel vertical accumulators; the row loop is fully
  // unrolled so every index below is compile-time.
  float acc[7][5];
#pragma unroll
  for (int s = 0; s < 7; ++s)
#pragma unroll
    for (int c = 0; c < 5; ++c) acc[s][c] = 0.f;
  float tsum = 0.f;

  // One-row register prefetch (4 VGPRs; proven no-spill in R1).
  float pxa, pya, pxb, pyb;
  auto load_row = [&](int r) {
    const int gy = y0 - 3 + r;
    pxa = 0.f; pya = 0.f; pxb = 0.f; pyb = 0.f;
    if ((unsigned)gy < (unsigned)IMG_H) {   // wave-uniform
      const float* xrow = Xb + (size_t)gy * IMG_W;
      const float* yrow = Yb + (size_t)gy * IMG_W;
      if (ok1) { pxa = xrow[g1]; pya = yrow[g1]; }
      if (ok2) { pxb = xrow[g2]; pyb = yrow[g2]; }
    }
  };

  load_row(0);

#pragma unroll
  for (int r = 0; r < NROWS; ++r) {   // fully unrolled: r compile-time
    const int buf = r & 1;

    sbuf[buf][t] = make_float2(pxa, pya);
    if (t < 6) sbuf[buf][TW + t] = make_float2(pxb, pyb);

    if (r + 1 < NROWS) load_row(r + 1);  // issue next row's global loads

    __syncthreads();

    // horizontal 7-tap, 5 channels (7 ds_read_b64)
    float hx = 0.f, hy = 0.f, hxx = 0.f, hyy = 0.f, hxy = 0.f;
#pragma unroll
    for (int k = 0; k < 7; ++k) {
      const float2 p = sbuf[buf][t + k];
      const float wx = w[k] * p.x;
      const float wy = w[k] * p.y;
      hx  = fmaf(w[k], p.x, hx);
      hy  = fmaf(w[k], p.y, hy);
      hxx = fmaf(wx, p.x, hxx);
      hyy = fmaf(wy, p.y, hyy);
      hxy = fmaf(wx, p.y, hxy);
    }

    // vertical scatter into the ring; guards fold at compile time
#pragma unroll
    for (int tt = 0; tt < 7; ++tt) {
      const int o = r - tt;
      if (o >= 0 && o < TH) {
        const int slot = o % 7;
        const float wt = w[tt];
        acc[slot][0] = fmaf(wt, hx,  acc[slot][0]);
        acc[slot][1] = fmaf(wt, hy,  acc[slot][1]);
        acc[slot][2] = fmaf(wt, hxx, acc[slot][2]);
        acc[slot][3] = fmaf(wt, hyy, acc[slot][3]);
        acc[slot][4] = fmaf(wt, hxy, acc[slot][4]);
      }
    }

    // output row r-6 complete
    if (r >= 6 && r - 6 < TH) {
      const int slot = (r - 6) % 7;
      const float mu_x = acc[slot][0];
      const float mu_y = acc[slot][1];
      const float mx2 = mu_x * mu_x;
      const float my2 = mu_y * mu_y;
      const float mxy = mu_x * mu_y;
      const float sxx = acc[slot][2] - mx2;
      const float syy = acc[slot][3] - my2;
      const float sxy = acc[slot][4] - mxy;
      const float num = (2.f * mxy + 1e-4f) * (2.f * sxy + 9e-4f);
      const float den = (mx2 + my2 + 1e-4f) * (sxx + syy + 9e-4f);
      tsum += num * __builtin_amdgcn_rcpf(den);
#pragma unroll
      for (int c = 0; c < 5; ++c) acc[slot][c] = 0.f;
    }
  }

  // Block reduction -> one plain store per block (no atomics, no fences).
#pragma unroll
  for (int off = 32; off > 0; off >>= 1) tsum += __shfl_down(tsum, off);
  if ((t & 63) == 0) wsum[t >> 6] = tsum;
  __syncthreads();
  if (t == 0) {
    const int bid = blockIdx.x + 2 * (blockIdx.y + 32 * blockIdx.z);
    partials[bid] = wsum[0] + wsum[1] + wsum[2] + wsum[3];
  }
}

__global__ __launch_bounds__(256) void ssim_reduce(
    const float* __restrict__ partials, float* __restrict__ out) {
  __shared__ double wsum[4];
  const int t = threadIdx.x;
  double s = 0.0;
#pragma unroll
  for (int i = 0; i < NBLK / 256; ++i) s += (double)partials[t + 256 * i];
#pragma unroll
  for (int off = 32; off > 0; off >>= 1) s += __shfl_down(s, off);
  if ((t & 63) == 0) wsum[t >> 6] = s;
  __syncthreads();
  if (t == 0)
    out[0] = (float)((wsum[0] + wsum[1] + wsum[2] + wsum[3]) *
                     (1.0 / (double)((size_t)BATCH * IMG_H * IMG_W)));
}

extern "C" void kernel_launch(void* const* d_in, const int* in_sizes, int n_in,
                              void* d_out, int out_size, void* d_ws, size_t ws_size,
                              hipStream_t stream) {
  const float* X = (const float*)d_in[0];
  const float* Y = (const float*)d_in[1];
  const float* K = (const float*)d_in[2];
  float* out = (float*)d_out;
  float* partials = (float*)d_ws;   // NBLK floats, all rewritten every launch

  dim3 grid(IMG_W / TW, IMG_H / TH, BATCH);  // (2, 32, 32) = 2048 blocks
  hipLaunchKernelGGL(ssim_main, grid, dim3(256), 0, stream, X, Y, K, partials);
  hipLaunchKernelGGL(ssim_reduce, dim3(1), dim3(256), 0, stream, partials, out);
}